// Round 17
// baseline (43.754 us; speedup 1.0000x reference)
//
#include <hip/hip_runtime.h>
#include <math.h>

#define IMG_H 512
#define IMG_W 512
#define SW 256        // strip width per wave (f32 cols)
#define RING 5        // LDS row ring per wave
#define BAND 16       // output rows per wave

typedef float f32x4 __attribute__((ext_vector_type(4)));
typedef float f32x2 __attribute__((ext_vector_type(2)));

__device__ __forceinline__ int reflect101(int i, int n) {
    if (i < 0) i = -i;
    if (i >= n) i = 2 * n - 2 - i;
    return i;
}

// fire-and-forget 16B/lane global->LDS DMA; LDS dest = uniform base + lane*16
__device__ __forceinline__ void gl_lds16(const float* g, float* l) {
    __builtin_amdgcn_global_load_lds(
        (const __attribute__((address_space(1))) unsigned int*)g,
        (__attribute__((address_space(3))) unsigned int*)l, 16, 0, 0);
}

#define SCHED0 __builtin_amdgcn_sched_barrier(0)
#define WAITV(N) do { SCHED0; asm volatile("s_waitcnt vmcnt(" #N ")" ::: "memory"); SCHED0; } while (0)

// Stage src row V (strip-local 0..19) into ring slot V%5: main DMA + halo DMA = 2 vmcnt ops.
#define STAGE(V) do {                                                         \
    const int sl_ = (V) % RING;                                               \
    const int gy_ = reflect101(ty0 + (V) - 2, IMG_H);                         \
    const float* rp_ = ip + (size_t)gy_ * IMG_W;                              \
    gl_lds16(rp_ + tx0 + 4 * l, mw + sl_ * SW);                               \
    if (l < 2) gl_lds16(rp_ + (l ? gx1 : gx0), hw + sl_ * 8);                 \
} while (0)

// Issue LDS reads of ring slot SLOT into register set S (consumed NEXT iter; lgkm
// latency hides under a full row of compute). S is compile-time after unroll.
#define LDRS(SLOT, S) do {                                                    \
    const float* rb_ = mw + (SLOT) * SW;                                      \
    MM0[S] = *(const f32x4*)(rb_ + ga);                                       \
    MM1[S] = *(const f32x4*)(rb_ + gb);                                       \
    MM2[S] = *(const f32x4*)(rb_ + gc);                                       \
    HH[S]  = *(const f32x2*)(hw + (SLOT) * 8 + hoff);                         \
} while (0)

// Quantize 8 cols xo-2..xo+5 from register set S. floor(v*255) exact for uniform[0,1).
#define QRS(S, Q) do {                                                        \
    float a0_ = L ? (le ? MM1[S].z : HH[S].x) : MM0[S].z;                     \
    float a1_ = L ? (le ? MM1[S].y : HH[S].y) : MM0[S].w;                     \
    float a6_ = R ? (re ? MM1[S].z : HH[S].x) : MM2[S].x;                     \
    float a7_ = R ? (re ? MM1[S].y : HH[S].y) : MM2[S].y;                     \
    Q[0] = floorf(a0_ * 255.0f);      Q[1] = floorf(a1_ * 255.0f);            \
    Q[2] = floorf(MM1[S].x * 255.0f); Q[3] = floorf(MM1[S].y * 255.0f);       \
    Q[4] = floorf(MM1[S].z * 255.0f); Q[5] = floorf(MM1[S].w * 255.0f);       \
    Q[6] = floorf(a6_ * 255.0f);      Q[7] = floorf(a7_ * 255.0f);            \
} while (0)

#define EMK(E, QA, QB) do {                                                   \
    _Pragma("unroll") for (int j_ = 0; j_ < 8; ++j_) E[j_] = QA[j_] + QB[j_]; \
} while (0)

// 6-wide blur row from two 8-wide e-rows. Sums <=4080 exact; rintf == jnp.round.
#define BLM(BL, EA, EB) do {                                                  \
    float cs_[8], d_[7];                                                      \
    _Pragma("unroll") for (int j_ = 0; j_ < 8; ++j_) cs_[j_] = EA[j_] + EB[j_]; \
    _Pragma("unroll") for (int j_ = 0; j_ < 7; ++j_) d_[j_] = cs_[j_] + cs_[j_ + 1]; \
    _Pragma("unroll") for (int j_ = 0; j_ < 6; ++j_)                          \
        BL[j_] = rintf((d_[j_] + d_[j_ + 1]) * 0.0625f);                      \
} while (0)

// Laplacian + |.| + clip, 4 cols, ONE b128 store (lane-contiguous, 1 vmcnt op).
#define OUTR(BA, BB, BC, T) do {                                              \
    float u_[6];                                                              \
    _Pragma("unroll") for (int j_ = 0; j_ < 6; ++j_) u_[j_] = BA[j_] + BC[j_]; \
    f32x4 o_; float h_;                                                       \
    h_ = fmaf(-4.0f, BB[1], u_[0] + u_[2]); o_.x = fminf(2.0f * fabsf(h_), 255.0f); \
    h_ = fmaf(-4.0f, BB[2], u_[1] + u_[3]); o_.y = fminf(2.0f * fabsf(h_), 255.0f); \
    h_ = fmaf(-4.0f, BB[3], u_[2] + u_[4]); o_.z = fminf(2.0f * fabsf(h_), 255.0f); \
    h_ = fmaf(-4.0f, BB[4], u_[3] + u_[5]); o_.w = fminf(2.0f * fabsf(h_), 255.0f); \
    *(f32x4*)&op[(size_t)(ty0 + (T)) * IMG_W + xo] = o_;                      \
} while (0)

__global__ __launch_bounds__(256, 8) void lap_fused(const float* __restrict__ in,
                                                    float* __restrict__ out) {
    __shared__ float s_m[4][RING][SW];   // 20480 B: per-wave private row rings
    __shared__ float s_h[4][RING][8];    //   640 B: per-wave halo rings

    const int tid = threadIdx.x;
    const int wv = tid >> 6;
    const int l = tid & 63;

    // wave-task: 96 imgs x 2 x-halves x 32 y-bands(16 rows) = 6144 waves, no barriers
    const int wg = blockIdx.x * 4 + wv;
    const int img = wg >> 6;
    const int t = wg & 63;
    const int xh = t >> 5;
    const int yb = t & 31;
    const int tx0 = xh * SW;
    const int ty0 = yb * BAND;

    const float* __restrict__ ip = in + (size_t)img * (IMG_H * IMG_W);
    float* __restrict__ op = out + (size_t)img * (IMG_H * IMG_W);

    float* mw = &s_m[wv][0][0];
    float* hw = &s_h[wv][0][0];

    const bool le = (xh == 0);
    const bool re = (xh == 1);
    const int gx0 = le ? 0 : (tx0 - 4);
    const int gx1 = re ? (IMG_W - 4) : (tx0 + SW);

    const bool L = (l == 0), R = (l == 63);
    const int ga = L ? 0 : 4 * (l - 1);
    const int gb = 4 * l;
    const int gc = R ? 4 * 63 : 4 * (l + 1);
    const int hoff = R ? 4 : 2;
    const int xo = tx0 + 4 * l;

    f32x4 MM0[2], MM1[2], MM2[2];
    f32x2 HH[2];
    float qq[2][8], el[2][8], bl[3][6];
    float e0t[8], e1t[8];

    // ---- prologue: stage rows 0..4 (slots 0..4, 10 vmcnt ops)
    #pragma unroll
    for (int s = 0; s < 5; ++s) STAGE(s);
    WAITV(6);                                  // rows 0,1 landed (stages 2,3,4 in flight)

    LDRS(0, 1); QRS(1, qq[0]);                 // q0
    LDRS(1, 1); QRS(1, qq[1]);                 // q1
    EMK(e0t, qq[0], qq[1]);                    // e0
    WAITV(2);                                  // rows 2,3 landed (stage 4 in flight)
    LDRS(2, 1); QRS(1, qq[0]);                 // q2
    EMK(e1t, qq[1], qq[0]);                    // e1
    BLM(bl[2], e0t, e1t);                      // bl(-1)
    LDRS(3, 1); QRS(1, qq[1]);                 // q3
    EMK(el[0], qq[0], qq[1]);                  // e2
    BLM(bl[0], e1t, el[0]);                    // bl(0)

    STAGE(5); STAGE(6);                        // slots 0,1 (their rows already read)
    WAITV(4);                                  // row 4 landed (stages 5,6 in flight)
    LDRS(4, 0);                                // prime set 0 with src row 4

    // ---- steady: read-ahead pipeline — consume set r&1 (row r+4, reads issued
    // last iter), issue LDRS(row r+5) into the other set, STAGE row r+7.
    #pragma unroll
    for (int r = 0; r < BAND; ++r) {
        // wait for DMA of src row r+5 (needed by this iter's LDRS)
        if (r == 0)       WAITV(2);
        else if (r == 1)  WAITV(3);
        else if (r == 14) WAITV(2);
        else if (r < 15)  WAITV(4);
        // r == 15: nothing left to wait for

        if (r + 7 <= 19) STAGE(r + 7);                       // slot (r+2)%5, free
        if (r + 5 <= 19) LDRS((r + 5) % RING, (r + 1) & 1);  // reads for next iter

        QRS(r & 1, qq[r & 1]);                               // q(r+4)
        EMK(el[(r + 1) & 1], qq[(r + 1) & 1], qq[r & 1]);    // e(r+3)
        BLM(bl[(r + 1) % 3], el[r & 1], el[(r + 1) & 1]);    // bl(r+1)
        OUTR(bl[(r + 2) % 3], bl[r % 3], bl[(r + 1) % 3], r);
    }
}

extern "C" void kernel_launch(void* const* d_in, const int* in_sizes, int n_in,
                              void* d_out, int out_size, void* d_ws, size_t ws_size,
                              hipStream_t stream) {
    const float* x = (const float*)d_in[0];
    float* out = (float*)d_out;
    dim3 grid(1536);  // 6144 waves / 4 per block = 6 blocks/CU exact, tail-free
    dim3 block(256);
    lap_fused<<<grid, block, 0, stream>>>(x, out);
}

// Round 18
// 38.540 us; speedup vs baseline: 1.1353x; 1.1353x over previous
//
#include <hip/hip_runtime.h>
#include <math.h>

#define IMG_H 512
#define IMG_W 512
#define SW 256        // strip width per wave (f32 cols)
#define RING 5        // LDS row ring per wave (3 live slots + 2 margin)
#define BAND 16       // output rows per wave

typedef float f32x4 __attribute__((ext_vector_type(4)));
typedef float f32x2 __attribute__((ext_vector_type(2)));

__device__ __forceinline__ int reflect101(int i, int n) {
    if (i < 0) i = -i;
    if (i >= n) i = 2 * n - 2 - i;
    return i;
}

// fire-and-forget 16B/lane global->LDS DMA; LDS dest = uniform base + lane*16
__device__ __forceinline__ void gl_lds16(const float* g, float* l) {
    __builtin_amdgcn_global_load_lds(
        (const __attribute__((address_space(1))) unsigned int*)g,
        (__attribute__((address_space(3))) unsigned int*)l, 16, 0, 0);
}

#define SCHED0 __builtin_amdgcn_sched_barrier(0)
#define WAITV(N) do { SCHED0; asm volatile("s_waitcnt vmcnt(" #N ")" ::: "memory"); SCHED0; } while (0)

// Stage src row V (strip-local 0..19) into ring slot V%5: 1 main DMA + 1 halo DMA (2 vmcnt ops).
#define STAGE(V) do {                                                         \
    const int sl_ = (V) % RING;                                               \
    const int gy_ = reflect101(ty0 + (V) - 2, IMG_H);                         \
    const float* rp_ = ip + (size_t)gy_ * IMG_W;                              \
    gl_lds16(rp_ + tx0 + 4 * l, mw + sl_ * SW);                               \
    if (l < 2) gl_lds16(rp_ + (l ? gx1 : gx0), hw + sl_ * 8);                 \
} while (0)

// Read one staged row: 3 b128 granules + halo b64 (per-lane cols xo-2..xo+5)
#define LDR(SLOT) do {                                                        \
    const float* rb_ = mw + (SLOT) * SW;                                      \
    M0 = *(const f32x4*)(rb_ + ga);                                           \
    M1 = *(const f32x4*)(rb_ + gb);                                           \
    M2 = *(const f32x4*)(rb_ + gc);                                           \
    H  = *(const f32x2*)(hw + (SLOT) * 8 + hoff);                             \
} while (0)

// Quantize 8 cols xo-2..xo+5. floor(v*255) exact for uniform[0,1) input.
#define QR(Q) do {                                                            \
    float a0_ = L ? (le ? M1.z : H.x) : M0.z;                                 \
    float a1_ = L ? (le ? M1.y : H.y) : M0.w;                                 \
    float a6_ = R ? (re ? M1.z : H.x) : M2.x;                                 \
    float a7_ = R ? (re ? M1.y : H.y) : M2.y;                                 \
    Q[0] = floorf(a0_ * 255.0f);  Q[1] = floorf(a1_ * 255.0f);                \
    Q[2] = floorf(M1.x * 255.0f); Q[3] = floorf(M1.y * 255.0f);               \
    Q[4] = floorf(M1.z * 255.0f); Q[5] = floorf(M1.w * 255.0f);               \
    Q[6] = floorf(a6_ * 255.0f);  Q[7] = floorf(a7_ * 255.0f);                \
} while (0)

#define EMK(E, QA, QB) do {                                                   \
    _Pragma("unroll") for (int j_ = 0; j_ < 8; ++j_) E[j_] = QA[j_] + QB[j_]; \
} while (0)

// 6-wide blur row from two 8-wide e-rows. Sums <=4080 exact; rintf == jnp.round.
#define BLM(BL, EA, EB) do {                                                  \
    float cs_[8], d_[7];                                                      \
    _Pragma("unroll") for (int j_ = 0; j_ < 8; ++j_) cs_[j_] = EA[j_] + EB[j_]; \
    _Pragma("unroll") for (int j_ = 0; j_ < 7; ++j_) d_[j_] = cs_[j_] + cs_[j_ + 1]; \
    _Pragma("unroll") for (int j_ = 0; j_ < 6; ++j_)                          \
        BL[j_] = rintf((d_[j_] + d_[j_ + 1]) * 0.0625f);                      \
} while (0)

// Laplacian + |.| + clip, 4 cols, ONE b128 store (lane-contiguous -> no write amp).
#define OUTR(BA, BB, BC, T) do {                                              \
    float u_[6];                                                              \
    _Pragma("unroll") for (int j_ = 0; j_ < 6; ++j_) u_[j_] = BA[j_] + BC[j_]; \
    f32x4 o_; float h_;                                                       \
    h_ = fmaf(-4.0f, BB[1], u_[0] + u_[2]); o_.x = fminf(2.0f * fabsf(h_), 255.0f); \
    h_ = fmaf(-4.0f, BB[2], u_[1] + u_[3]); o_.y = fminf(2.0f * fabsf(h_), 255.0f); \
    h_ = fmaf(-4.0f, BB[3], u_[2] + u_[4]); o_.z = fminf(2.0f * fabsf(h_), 255.0f); \
    h_ = fmaf(-4.0f, BB[4], u_[3] + u_[5]); o_.w = fminf(2.0f * fabsf(h_), 255.0f); \
    *(f32x4*)&op[(size_t)(ty0 + (T)) * IMG_W + xo] = o_;                      \
} while (0)

__global__ __launch_bounds__(256) void lap_fused(const float* __restrict__ in,
                                                 float* __restrict__ out) {
    __shared__ float s_m[4][RING][SW];   // 20480 B: per-wave private row rings
    __shared__ float s_h[4][RING][8];    //   640 B: per-wave halo rings -> 21120 B total

    const int tid = threadIdx.x;
    const int wv = tid >> 6;
    const int l = tid & 63;

    // wave-task: 96 imgs x 2 x-halves x 32 y-bands(16 rows) = 6144 waves, no barriers
    const int wg = blockIdx.x * 4 + wv;
    const int img = wg >> 6;
    const int t = wg & 63;
    const int xh = t >> 5;
    const int yb = t & 31;
    const int tx0 = xh * SW;
    const int ty0 = yb * BAND;

    const float* __restrict__ ip = in + (size_t)img * (IMG_H * IMG_W);
    float* __restrict__ op = out + (size_t)img * (IMG_H * IMG_W);

    float* mw = &s_m[wv][0][0];
    float* hw = &s_h[wv][0][0];

    const bool le = (xh == 0);
    const bool re = (xh == 1);
    const int gx0 = le ? 0 : (tx0 - 4);
    const int gx1 = re ? (IMG_W - 4) : (tx0 + SW);

    const bool L = (l == 0), R = (l == 63);
    const int ga = L ? 0 : 4 * (l - 1);
    const int gb = 4 * l;
    const int gc = R ? 4 * 63 : 4 * (l + 1);
    const int hoff = R ? 4 : 2;
    const int xo = tx0 + 4 * l;

    f32x4 M0, M1, M2; f32x2 H;
    float qq[2][8], el[2][8], bl[3][6];
    float e0t[8], e1t[8];

    // ---- prologue: stage rows 0..4 (10 vmcnt ops); rows 0..3 -> initial state
    #pragma unroll
    for (int s = 0; s < 5; ++s) STAGE(s);
    WAITV(2);                                  // rows 0..3 landed (row 4 = 2 ops in flight)

    LDR(0); QR(qq[0]);                         // q0
    LDR(1); QR(qq[1]);                         // q1
    EMK(e0t, qq[0], qq[1]);                    // e0
    LDR(2); QR(qq[0]);                         // q2
    EMK(e1t, qq[1], qq[0]);                    // e1
    BLM(bl[2], e0t, e1t);                      // bl(-1)
    LDR(3); QR(qq[1]);                         // q3
    EMK(el[0], qq[0], qq[1]);                  // e2
    BLM(bl[0], e1t, el[0]);                    // bl(0)

    // ---- steady: 1 row staged 2 ahead + 1 row computed per iter; counted vmcnt only
    #pragma unroll
    for (int r = 0; r < BAND; ++r) {
        if (r == 0)           { STAGE(5); STAGE(6); }
        else if (r + 6 <= 19) { STAGE(r + 6); }
        // wait for src local row r+4; N = vmem ops issued after its STAGE
        if (r == 0)       WAITV(4);
        else if (r == 1)  WAITV(5);
        else if (r == 14) WAITV(4);
        else if (r == 15) WAITV(2);
        else              WAITV(6);

        LDR((r + 4) % RING);                               // src row r+4
        QR(qq[r & 1]);                                     // q(r+4)
        EMK(el[(r + 1) & 1], qq[(r + 1) & 1], qq[r & 1]);  // e(r+3)
        BLM(bl[(r + 1) % 3], el[r & 1], el[(r + 1) & 1]);  // bl(r+1)
        OUTR(bl[(r + 2) % 3], bl[r % 3], bl[(r + 1) % 3], r);
    }
}

extern "C" void kernel_launch(void* const* d_in, const int* in_sizes, int n_in,
                              void* d_out, int out_size, void* d_ws, size_t ws_size,
                              hipStream_t stream) {
    const float* x = (const float*)d_in[0];
    float* out = (float*)d_out;
    dim3 grid(1536);  // 6144 waves / 4 per block = 6 blocks/CU exact (LDS cap 7), tail-free
    dim3 block(256);
    lap_fused<<<grid, block, 0, stream>>>(x, out);
}